// Round 3
// baseline (400.353 us; speedup 1.0000x reference)
//
#include <hip/hip_runtime.h>
#include <hip/hip_bf16.h>
#include <math.h>

// Problem: B=4, SEQ=1024, D_MODEL=1024, H=16, DH=64.
// Harness dtypes: float32 inputs/outputs (per reference), int32 mask.
// Internal compute: bf16 MFMA (f32 accum).
#define SEQ   1024
#define DM    1024
#define NH    16
#define DH    64
#define INV_SCALE 0.125f       // 1/sqrt(64)
#define NEGBIG   -1e9f

typedef __attribute__((ext_vector_type(8))) __bf16 bf16x8;
typedef __attribute__((ext_vector_type(4))) float floatx4;
typedef unsigned short ushort_t;

__device__ __forceinline__ floatx4 mfma16(bf16x8 a, bf16x8 b, floatx4 c) {
    return __builtin_amdgcn_mfma_f32_16x16x32_bf16(a, b, c, 0, 0, 0);
}

__device__ __forceinline__ ushort_t f2bf(float f) {
    unsigned int u = __float_as_uint(f);
    u += 0x7fffu + ((u >> 16) & 1u);      // RNE
    return (ushort_t)(u >> 16);
}

// ---------------- K0: f32 -> bf16 cast (8 elems/thread) ----------------
__global__ __launch_bounds__(256) void k_cast(const float* __restrict__ src,
                                              ushort_t* __restrict__ dst) {
    int i = (blockIdx.x * 256 + threadIdx.x) * 8;
    float4 a = *(const float4*)(src + i);
    float4 b = *(const float4*)(src + i + 4);
    union { ushort_t s[8]; uint4 v; } pk;
    pk.s[0] = f2bf(a.x); pk.s[1] = f2bf(a.y); pk.s[2] = f2bf(a.z); pk.s[3] = f2bf(a.w);
    pk.s[4] = f2bf(b.x); pk.s[5] = f2bf(b.y); pk.s[6] = f2bf(b.z); pk.s[7] = f2bf(b.w);
    *(uint4*)(dst + i) = pk.v;
}

// ---------------- K1: f32 (R x C) -> bf16 transpose (C x R) ----------------
__global__ __launch_bounds__(256) void k_transpose(const float* __restrict__ src,
                                                   ushort_t* __restrict__ dst,
                                                   int R, int C) {
    __shared__ ushort_t tile[32][33];
    int bx = blockIdx.x * 32;  // col base in src
    int by = blockIdx.y * 32;  // row base in src
    for (int i = threadIdx.y; i < 32; i += 8)
        tile[i][threadIdx.x] = f2bf(src[(size_t)(by + i) * C + bx + threadIdx.x]);
    __syncthreads();
    for (int i = threadIdx.y; i < 32; i += 8)
        dst[(size_t)(bx + i) * R + by + threadIdx.x] = tile[threadIdx.x][i];
}

// ------------- shared 128x128 MFMA GEMM body: C = A(MxK) * Bt(NxK)^T -------------
// smem: [0,4096) ushorts = A tile 128x32, [4096,8192) = B tile 128x32
__device__ __forceinline__ void gemm128_body(const ushort_t* __restrict__ A,
                                             const ushort_t* __restrict__ Bt,
                                             int m0, int n0, int Kd,
                                             floatx4 acc[4][4], ushort_t* smem) {
    int tid  = threadIdx.x;
    int wave = tid >> 6, lane = tid & 63;
    int l15 = lane & 15, quad = lane >> 4;
    int wr = (wave >> 1) * 64, wc = (wave & 1) * 64;

    int c0 = tid, c1 = tid + 256;
    int r0 = c0 >> 2, o0 = (c0 & 3) * 8;
    int r1 = c1 >> 2, o1 = (c1 & 3) * 8;

    for (int k0 = 0; k0 < Kd; k0 += 32) {
        uint4 a0 = *(const uint4*)(A  + (size_t)(m0 + r0) * Kd + k0 + o0);
        uint4 a1 = *(const uint4*)(A  + (size_t)(m0 + r1) * Kd + k0 + o1);
        uint4 b0 = *(const uint4*)(Bt + (size_t)(n0 + r0) * Kd + k0 + o0);
        uint4 b1 = *(const uint4*)(Bt + (size_t)(n0 + r1) * Kd + k0 + o1);
        __syncthreads();   // previous compute done before overwrite
        *(uint4*)(smem + r0 * 32 + o0)        = a0;
        *(uint4*)(smem + r1 * 32 + o1)        = a1;
        *(uint4*)(smem + 4096 + r0 * 32 + o0) = b0;
        *(uint4*)(smem + 4096 + r1 * 32 + o1) = b1;
        __syncthreads();   // tiles visible

        bf16x8 af[4], bfr[4];
        #pragma unroll
        for (int i = 0; i < 4; ++i)
            af[i] = *(const bf16x8*)(smem + (wr + i * 16 + l15) * 32 + quad * 8);
        #pragma unroll
        for (int j = 0; j < 4; ++j)
            bfr[j] = *(const bf16x8*)(smem + 4096 + (wc + j * 16 + l15) * 32 + quad * 8);
        #pragma unroll
        for (int i = 0; i < 4; ++i)
            #pragma unroll
            for (int j = 0; j < 4; ++j)
                acc[i][j] = mfma16(af[i], bfr[j], acc[i][j]);
    }
}

// ---------------- K2: QKV GEMM, epilogue routes Q/K/(V transposed) ----------------
__global__ __launch_bounds__(256, 2) void k_qkv_gemm(const ushort_t* __restrict__ X,
                                                     const ushort_t* __restrict__ Wt,
                                                     const float* __restrict__ bias,
                                                     ushort_t* __restrict__ qb,
                                                     ushort_t* __restrict__ kb,
                                                     ushort_t* __restrict__ vtb) {
    __shared__ ushort_t smem[8192];
    int m0 = blockIdx.y * 128, n0 = blockIdx.x * 128;
    floatx4 acc[4][4];
    #pragma unroll
    for (int i = 0; i < 4; ++i)
        #pragma unroll
        for (int j = 0; j < 4; ++j) acc[i][j] = (floatx4)0.0f;

    gemm128_body(X, Wt, m0, n0, DM, acc, smem);

    int tid = threadIdx.x, wave = tid >> 6, lane = tid & 63;
    int l15 = lane & 15, quad = lane >> 4;
    int wr = (wave >> 1) * 64, wc = (wave & 1) * 64;
    #pragma unroll
    for (int i = 0; i < 4; ++i) {
        int mrow0 = m0 + wr + i * 16 + quad * 4;     // multiple of 4, no b-crossing
        int b = mrow0 >> 10, t0 = mrow0 & 1023;
        #pragma unroll
        for (int j = 0; j < 4; ++j) {
            int n = n0 + wc + j * 16 + l15;
            float bv = bias[n];
            int sec = n >> 10, nn = n & 1023;
            int h = nn >> 6, d = nn & 63;
            if (sec == 2) {
                union { ushort_t s[4]; uint2 v; } pk;
                #pragma unroll
                for (int r = 0; r < 4; ++r) pk.s[r] = f2bf(acc[i][j][r] + bv);
                *(uint2*)(vtb + (((size_t)(b * NH + h) * DH + d) * SEQ + t0)) = pk.v;
            } else {
                ushort_t* dst = (sec == 0) ? qb : kb;
                #pragma unroll
                for (int r = 0; r < 4; ++r)
                    dst[((size_t)(b * NH + h) * SEQ + t0 + r) * DH + d] =
                        f2bf(acc[i][j][r] + bv);
            }
        }
    }
}

// ---------------- K3pre: softmax stats m, 1/l per (b,h,q) row ----------------
__global__ __launch_bounds__(256, 2) void k_stats(const ushort_t* __restrict__ qb,
                                                  const ushort_t* __restrict__ kb,
                                                  const int* __restrict__ mask,
                                                  float* __restrict__ mbuf,
                                                  float* __restrict__ lbuf) {
    int bh = blockIdx.x, qt = blockIdx.y;
    int b = bh >> 4;
    int tid = threadIdx.x, wave = tid >> 6, lane = tid & 63;
    int l15 = lane & 15, quad = lane >> 4;
    int qrow = qt * 64 + wave * 16;

    const ushort_t* qbase = qb + ((size_t)bh * SEQ + qrow + l15) * DH;
    bf16x8 aq0 = *(const bf16x8*)(qbase + quad * 8);
    bf16x8 aq1 = *(const bf16x8*)(qbase + 32 + quad * 8);

    float qm[4], mrun[4], lrun[4];
    #pragma unroll
    for (int r = 0; r < 4; ++r) {
        qm[r] = (float)mask[b * SEQ + qrow + quad * 4 + r];
        mrun[r] = -3.0e38f; lrun[r] = 0.0f;
    }

    for (int kc = 0; kc < SEQ; kc += 64) {
        floatx4 s[4];
        #pragma unroll
        for (int j = 0; j < 4; ++j) {
            s[j] = (floatx4)0.0f;
            const ushort_t* kbase = kb + ((size_t)bh * SEQ + kc + j * 16 + l15) * DH;
            s[j] = mfma16(aq0, *(const bf16x8*)(kbase + quad * 8), s[j]);
            s[j] = mfma16(aq1, *(const bf16x8*)(kbase + 32 + quad * 8), s[j]);
        }
        #pragma unroll
        for (int j = 0; j < 4; ++j) {
            float km = (float)mask[b * SEQ + kc + j * 16 + l15];
            #pragma unroll
            for (int r = 0; r < 4; ++r)
                s[j][r] = s[j][r] * INV_SCALE + (1.0f - qm[r] * km) * NEGBIG;
        }
        #pragma unroll
        for (int r = 0; r < 4; ++r) {
            float cm = fmaxf(fmaxf(s[0][r], s[1][r]), fmaxf(s[2][r], s[3][r]));
            #pragma unroll
            for (int off = 1; off < 16; off <<= 1) cm = fmaxf(cm, __shfl_xor(cm, off, 16));
            float nm = fmaxf(mrun[r], cm);
            float sum = __expf(s[0][r] - nm) + __expf(s[1][r] - nm) +
                        __expf(s[2][r] - nm) + __expf(s[3][r] - nm);
            #pragma unroll
            for (int off = 1; off < 16; off <<= 1) sum += __shfl_xor(sum, off, 16);
            lrun[r] = lrun[r] * __expf(mrun[r] - nm) + sum;
            mrun[r] = nm;
        }
    }
    if (l15 == 0) {
        #pragma unroll
        for (int r = 0; r < 4; ++r) {
            int row = qrow + quad * 4 + r;
            mbuf[(size_t)bh * SEQ + row] = mrun[r];
            lbuf[(size_t)bh * SEQ + row] = 1.0f / lrun[r];
        }
    }
}

// ---------------- K3a: O = softmax(S) @ V ----------------
__global__ __launch_bounds__(256, 2) void k_attn_o(const ushort_t* __restrict__ qb,
                                                   const ushort_t* __restrict__ kb,
                                                   const ushort_t* __restrict__ vtb,
                                                   const int* __restrict__ mask,
                                                   const float* __restrict__ mbuf,
                                                   const float* __restrict__ lbuf,
                                                   ushort_t* __restrict__ ob) {
    __shared__ ushort_t vs[64 * 64];     // V^T chunk [d][kk]
    __shared__ ushort_t ps[4 * 16 * 64]; // per-wave P tiles
    int bh = blockIdx.x, qt = blockIdx.y;
    int b = bh >> 4, h = bh & 15;
    int tid = threadIdx.x, wave = tid >> 6, lane = tid & 63;
    int l15 = lane & 15, quad = lane >> 4;
    int qrow = qt * 64 + wave * 16;
    ushort_t* pw = ps + wave * 1024;

    const ushort_t* qbase = qb + ((size_t)bh * SEQ + qrow + l15) * DH;
    bf16x8 aq0 = *(const bf16x8*)(qbase + quad * 8);
    bf16x8 aq1 = *(const bf16x8*)(qbase + 32 + quad * 8);

    float qm[4], mrow[4], invl[4];
    #pragma unroll
    for (int r = 0; r < 4; ++r) {
        int row = qrow + quad * 4 + r;
        qm[r]   = (float)mask[b * SEQ + row];
        mrow[r] = mbuf[(size_t)bh * SEQ + row];
        invl[r] = lbuf[(size_t)bh * SEQ + row];
    }
    floatx4 oacc[4];
    #pragma unroll
    for (int t = 0; t < 4; ++t) oacc[t] = (floatx4)0.0f;

    for (int kc = 0; kc < SEQ; kc += 64) {
        __syncthreads();   // previous PV reads of vs done
        for (int c = tid; c < 512; c += 256) {
            int d = c >> 3, col = c & 7;
            *(uint4*)(vs + d * 64 + col * 8) =
                *(const uint4*)(vtb + ((size_t)bh * DH + d) * SEQ + kc + col * 8);
        }
        floatx4 s[4];
        #pragma unroll
        for (int j = 0; j < 4; ++j) {
            s[j] = (floatx4)0.0f;
            const ushort_t* kbase = kb + ((size_t)bh * SEQ + kc + j * 16 + l15) * DH;
            s[j] = mfma16(aq0, *(const bf16x8*)(kbase + quad * 8), s[j]);
            s[j] = mfma16(aq1, *(const bf16x8*)(kbase + 32 + quad * 8), s[j]);
        }
        #pragma unroll
        for (int j = 0; j < 4; ++j) {
            float km = (float)mask[b * SEQ + kc + j * 16 + l15];
            #pragma unroll
            for (int r = 0; r < 4; ++r) {
                float sv = s[j][r] * INV_SCALE + (1.0f - qm[r] * km) * NEGBIG;
                float p  = __expf(sv - mrow[r]) * invl[r];
                pw[(quad * 4 + r) * 64 + j * 16 + l15] = f2bf(p);
            }
        }
        __syncthreads();   // vs staged & P visible

        bf16x8 pa0 = *(const bf16x8*)(pw + l15 * 64 + quad * 8);
        bf16x8 pa1 = *(const bf16x8*)(pw + l15 * 64 + 32 + quad * 8);
        #pragma unroll
        for (int t = 0; t < 4; ++t) {
            bf16x8 bv0 = *(const bf16x8*)(vs + (t * 16 + l15) * 64 + quad * 8);
            bf16x8 bv1 = *(const bf16x8*)(vs + (t * 16 + l15) * 64 + 32 + quad * 8);
            oacc[t] = mfma16(pa0, bv0, oacc[t]);
            oacc[t] = mfma16(pa1, bv1, oacc[t]);
        }
    }
    #pragma unroll
    for (int t = 0; t < 4; ++t)
        #pragma unroll
        for (int r = 0; r < 4; ++r)
            ob[((size_t)b * SEQ + qrow + quad * 4 + r) * DM + h * DH + t * 16 + l15] =
                f2bf(oacc[t][r]);
}

// ---------------- K3b: attn mean over heads (f32 out) ----------------
__global__ __launch_bounds__(256, 2) void k_attn_avg(const ushort_t* __restrict__ qb,
                                                     const ushort_t* __restrict__ kb,
                                                     const int* __restrict__ mask,
                                                     const float* __restrict__ mbuf,
                                                     const float* __restrict__ lbuf,
                                                     float* __restrict__ attn_out) {
    int b = blockIdx.x >> 6, qt = blockIdx.x & 63;   // 16 q-rows per block
    int q0 = qt * 16;
    int tid = threadIdx.x, wave = tid >> 6, lane = tid & 63;
    int l15 = lane & 15, quad = lane >> 4;
    int kbase = wave * 256;

    float qmr[4];
    #pragma unroll
    for (int r = 0; r < 4; ++r) qmr[r] = (float)mask[b * SEQ + q0 + quad * 4 + r];

    floatx4 aacc[4][4];
    #pragma unroll
    for (int sc = 0; sc < 4; ++sc)
        #pragma unroll
        for (int j = 0; j < 4; ++j) aacc[sc][j] = (floatx4)0.0f;

    for (int h = 0; h < NH; ++h) {
        int bh = b * NH + h;
        const ushort_t* qbase = qb + ((size_t)bh * SEQ + q0 + l15) * DH;
        bf16x8 aq0 = *(const bf16x8*)(qbase + quad * 8);
        bf16x8 aq1 = *(const bf16x8*)(qbase + 32 + quad * 8);
        float mr[4], il[4];
        #pragma unroll
        for (int r = 0; r < 4; ++r) {
            mr[r] = mbuf[(size_t)bh * SEQ + q0 + quad * 4 + r];
            il[r] = lbuf[(size_t)bh * SEQ + q0 + quad * 4 + r];
        }
        for (int sc = 0; sc < 4; ++sc) {
            int kc = kbase + sc * 64;
            floatx4 s[4];
            #pragma unroll
            for (int j = 0; j < 4; ++j) {
                s[j] = (floatx4)0.0f;
                const ushort_t* kp = kb + ((size_t)bh * SEQ + kc + j * 16 + l15) * DH;
                s[j] = mfma16(aq0, *(const bf16x8*)(kp + quad * 8), s[j]);
                s[j] = mfma16(aq1, *(const bf16x8*)(kp + 32 + quad * 8), s[j]);
            }
            #pragma unroll
            for (int j = 0; j < 4; ++j) {
                float km = (float)mask[b * SEQ + kc + j * 16 + l15];
                #pragma unroll
                for (int r = 0; r < 4; ++r) {
                    float sv = s[j][r] * INV_SCALE + (1.0f - qmr[r] * km) * NEGBIG;
                    aacc[sc][j][r] += __expf(sv - mr[r]) * il[r] * 0.0625f;
                }
            }
        }
    }
    #pragma unroll
    for (int sc = 0; sc < 4; ++sc)
        #pragma unroll
        for (int j = 0; j < 4; ++j)
            #pragma unroll
            for (int r = 0; r < 4; ++r)
                attn_out[((size_t)b * SEQ + q0 + quad * 4 + r) * SEQ +
                         kbase + sc * 64 + j * 16 + l15] = aacc[sc][j][r];
}

// ---------------- K4: output projection + bias + residual (f32 out) ----------------
__global__ __launch_bounds__(256, 2) void k_proj(const ushort_t* __restrict__ ob,
                                                 const ushort_t* __restrict__ Wpt,
                                                 const float* __restrict__ bias,
                                                 const float* __restrict__ tokens,
                                                 float* __restrict__ out) {
    __shared__ ushort_t smem[8192];
    int m0 = blockIdx.y * 128, n0 = blockIdx.x * 128;
    floatx4 acc[4][4];
    #pragma unroll
    for (int i = 0; i < 4; ++i)
        #pragma unroll
        for (int j = 0; j < 4; ++j) acc[i][j] = (floatx4)0.0f;

    gemm128_body(ob, Wpt, m0, n0, DM, acc, smem);

    int tid = threadIdx.x, wave = tid >> 6, lane = tid & 63;
    int l15 = lane & 15, quad = lane >> 4;
    int wr = (wave >> 1) * 64, wc = (wave & 1) * 64;
    #pragma unroll
    for (int i = 0; i < 4; ++i) {
        int m0r = m0 + wr + i * 16 + quad * 4;
        #pragma unroll
        for (int j = 0; j < 4; ++j) {
            int n = n0 + wc + j * 16 + l15;
            float bv = bias[n];
            #pragma unroll
            for (int r = 0; r < 4; ++r) {
                size_t idx = (size_t)(m0r + r) * DM + n;
                out[idx] = acc[i][j][r] + bv + tokens[idx];
            }
        }
    }
}

extern "C" void kernel_launch(void* const* d_in, const int* in_sizes, int n_in,
                              void* d_out, int out_size, void* d_ws, size_t ws_size,
                              hipStream_t stream) {
    const float* tokens = (const float*)d_in[0];
    const int*   mask   = (const int*)d_in[1];
    const float* Wqkv   = (const float*)d_in[2];
    const float* bqkv   = (const float*)d_in[3];
    const float* Wproj  = (const float*)d_in[4];
    const float* bproj  = (const float*)d_in[5];

    float* out_tok  = (float*)d_out;                   // 4M floats
    float* out_attn = out_tok + (size_t)4 * SEQ * SEQ; // 4M floats

    // scratch inside d_out's attn region (overwritten last by k_attn_avg):
    ushort_t* Xbf  = (ushort_t*)out_attn;                        // 4M bf16 = first 2M floats
    ushort_t* obuf = (ushort_t*)(out_attn + (size_t)2 * SEQ * SEQ); // 4M bf16 = last 2M floats

    // ws layout (32.75 MB)
    ushort_t* Wt   = (ushort_t*)d_ws;            // 3072x1024 bf16
    ushort_t* Wpt  = Wt  + (size_t)3 * DM * DM;  // 1024x1024 bf16
    ushort_t* qbuf = Wpt + (size_t)DM * DM;      // (b,h,s,d)
    ushort_t* kbuf = qbuf + (size_t)4 * SEQ * DM;
    ushort_t* vtb  = kbuf + (size_t)4 * SEQ * DM; // (b,h,d,s)
    float*    mbuf = (float*)(vtb + (size_t)4 * SEQ * DM);
    float*    lbuf = mbuf + (size_t)4 * NH * SEQ;

    k_cast<<<(4 * SEQ * DM) / (8 * 256), 256, 0, stream>>>(tokens, Xbf);
    k_transpose<<<dim3(3 * DM / 32, DM / 32), dim3(32, 8), 0, stream>>>(Wqkv, Wt, DM, 3 * DM);
    k_transpose<<<dim3(DM / 32, DM / 32), dim3(32, 8), 0, stream>>>(Wproj, Wpt, DM, DM);
    k_qkv_gemm<<<dim3(24, 32), 256, 0, stream>>>(Xbf, Wt, bqkv, qbuf, kbuf, vtb);
    k_stats<<<dim3(64, 16), 256, 0, stream>>>(qbuf, kbuf, mask, mbuf, lbuf);
    k_attn_o<<<dim3(64, 16), 256, 0, stream>>>(qbuf, kbuf, vtb, mask, mbuf, lbuf, obuf);
    k_proj<<<dim3(8, 32), 256, 0, stream>>>(obuf, Wpt, bproj, tokens, out_tok);
    k_attn_avg<<<256, 256, 0, stream>>>(qbuf, kbuf, mask, mbuf, lbuf, out_attn);
}

// Round 4
// 308.749 us; speedup vs baseline: 1.2967x; 1.2967x over previous
//
#include <hip/hip_runtime.h>
#include <hip/hip_bf16.h>
#include <math.h>

// Problem: B=4, SEQ=1024, D_MODEL=1024, H=16, DH=64.
// Harness dtypes: float32 inputs/outputs, int32 mask. Internal: bf16 MFMA.
#define SEQ   1024
#define DM    1024
#define NH    16
#define DH    64
#define INV_SCALE 0.125f       // 1/sqrt(64)
#define NEGBIG   -1e9f

typedef __attribute__((ext_vector_type(8))) __bf16 bf16x8;
typedef __attribute__((ext_vector_type(4))) float floatx4;
typedef unsigned short ushort_t;

__device__ __forceinline__ floatx4 mfma16(bf16x8 a, bf16x8 b, floatx4 c) {
    return __builtin_amdgcn_mfma_f32_16x16x32_bf16(a, b, c, 0, 0, 0);
}

__device__ __forceinline__ ushort_t f2bf(float f) {
    unsigned int u = __float_as_uint(f);
    u += 0x7fffu + ((u >> 16) & 1u);      // RNE
    return (ushort_t)(u >> 16);
}

__device__ __forceinline__ void gload_lds16(const void* g, void* l) {
    __builtin_amdgcn_global_load_lds(
        (const __attribute__((address_space(1))) unsigned int*)g,
        (__attribute__((address_space(3))) unsigned int*)l, 16, 0, 0);
}

// ---------------- K0: f32 -> bf16 cast (8 elems/thread) ----------------
__global__ __launch_bounds__(256) void k_cast(const float* __restrict__ src,
                                              ushort_t* __restrict__ dst) {
    int i = (blockIdx.x * 256 + threadIdx.x) * 8;
    float4 a = *(const float4*)(src + i);
    float4 b = *(const float4*)(src + i + 4);
    union { ushort_t s[8]; uint4 v; } pk;
    pk.s[0] = f2bf(a.x); pk.s[1] = f2bf(a.y); pk.s[2] = f2bf(a.z); pk.s[3] = f2bf(a.w);
    pk.s[4] = f2bf(b.x); pk.s[5] = f2bf(b.y); pk.s[6] = f2bf(b.z); pk.s[7] = f2bf(b.w);
    *(uint4*)(dst + i) = pk.v;
}

// ---------------- K1: f32 (R x C) -> bf16 transpose (C x R) ----------------
__global__ __launch_bounds__(256) void k_transpose(const float* __restrict__ src,
                                                   ushort_t* __restrict__ dst,
                                                   int R, int C) {
    __shared__ ushort_t tile[32][33];
    int bx = blockIdx.x * 32;
    int by = blockIdx.y * 32;
    for (int i = threadIdx.y; i < 32; i += 8)
        tile[i][threadIdx.x] = f2bf(src[(size_t)(by + i) * C + bx + threadIdx.x]);
    __syncthreads();
    for (int i = threadIdx.y; i < 32; i += 8)
        dst[(size_t)(bx + i) * R + by + threadIdx.x] = tile[threadIdx.x][i];
}

// ------------- shared 128x128 MFMA GEMM body: C = A(MxK) * Bt(NxK)^T -------------
// smem: [0,4096) ushorts = A tile 128x32, [4096,8192) = B tile 128x32
// Staging: global_load_lds width=16 (m97 ladder step). LDS dest is wave-uniform
// base + lane*16B; layout matches (lane i -> row i>>2, col (i&3)*8).
__device__ __forceinline__ void gemm128_body(const ushort_t* __restrict__ A,
                                             const ushort_t* __restrict__ Bt,
                                             int m0, int n0, int Kd,
                                             floatx4 acc[4][4], ushort_t* smem) {
    int tid  = threadIdx.x;
    int wave = tid >> 6, lane = tid & 63;
    int l15 = lane & 15, quad = lane >> 4;
    int wr = (wave >> 1) * 64, wc = (wave & 1) * 64;
    int rsub = lane >> 2;             // 0..15 row within 16-row chunk
    int ksub = (lane & 3) * 8;        // elem offset within 32-k slab

    for (int k0 = 0; k0 < Kd; k0 += 32) {
        __syncthreads();   // previous compute done before overwrite
        #pragma unroll
        for (int c = 0; c < 2; ++c) {
            int rbase = wave * 32 + c * 16;
            gload_lds16(A  + (size_t)(m0 + rbase + rsub) * Kd + k0 + ksub,
                        smem + rbase * 32);
            gload_lds16(Bt + (size_t)(n0 + rbase + rsub) * Kd + k0 + ksub,
                        smem + 4096 + rbase * 32);
        }
        __syncthreads();   // compiler drains vmcnt before barrier

        bf16x8 af[4], bfr[4];
        #pragma unroll
        for (int i = 0; i < 4; ++i)
            af[i] = *(const bf16x8*)(smem + (wr + i * 16 + l15) * 32 + quad * 8);
        #pragma unroll
        for (int j = 0; j < 4; ++j)
            bfr[j] = *(const bf16x8*)(smem + 4096 + (wc + j * 16 + l15) * 32 + quad * 8);
        #pragma unroll
        for (int i = 0; i < 4; ++i)
            #pragma unroll
            for (int j = 0; j < 4; ++j)
                acc[i][j] = mfma16(af[i], bfr[j], acc[i][j]);
    }
}

// ---------------- K2: QKV GEMM, epilogue routes Q/K/(V transposed) ----------------
__global__ __launch_bounds__(256, 2) void k_qkv_gemm(const ushort_t* __restrict__ X,
                                                     const ushort_t* __restrict__ Wt,
                                                     const float* __restrict__ bias,
                                                     ushort_t* __restrict__ qb,
                                                     ushort_t* __restrict__ kb,
                                                     ushort_t* __restrict__ vtb) {
    __shared__ ushort_t smem[8192];
    int m0 = blockIdx.y * 128, n0 = blockIdx.x * 128;
    floatx4 acc[4][4];
    #pragma unroll
    for (int i = 0; i < 4; ++i)
        #pragma unroll
        for (int j = 0; j < 4; ++j) acc[i][j] = (floatx4)0.0f;

    gemm128_body(X, Wt, m0, n0, DM, acc, smem);

    int tid = threadIdx.x, wave = tid >> 6, lane = tid & 63;
    int l15 = lane & 15, quad = lane >> 4;
    int wr = (wave >> 1) * 64, wc = (wave & 1) * 64;
    #pragma unroll
    for (int i = 0; i < 4; ++i) {
        int mrow0 = m0 + wr + i * 16 + quad * 4;     // multiple of 4, no b-crossing
        int b = mrow0 >> 10, t0 = mrow0 & 1023;
        #pragma unroll
        for (int j = 0; j < 4; ++j) {
            int n = n0 + wc + j * 16 + l15;
            float bv = bias[n];
            int sec = n >> 10, nn = n & 1023;
            int h = nn >> 6, d = nn & 63;
            if (sec == 2) {
                union { ushort_t s[4]; uint2 v; } pk;
                #pragma unroll
                for (int r = 0; r < 4; ++r) pk.s[r] = f2bf(acc[i][j][r] + bv);
                *(uint2*)(vtb + (((size_t)(b * NH + h) * DH + d) * SEQ + t0)) = pk.v;
            } else {
                ushort_t* dst = (sec == 0) ? qb : kb;
                #pragma unroll
                for (int r = 0; r < 4; ++r)
                    dst[((size_t)(b * NH + h) * SEQ + t0 + r) * DH + d] =
                        f2bf(acc[i][j][r] + bv);
            }
        }
    }
}

// ---------------- K3: flash attention — online softmax, O = P@V, writes m & 1/l ----
__global__ __launch_bounds__(256, 4) void k_attn_flash(const ushort_t* __restrict__ qb,
                                                       const ushort_t* __restrict__ kb,
                                                       const ushort_t* __restrict__ vtb,
                                                       const int* __restrict__ mask,
                                                       float* __restrict__ mbuf,
                                                       float* __restrict__ lbuf,
                                                       ushort_t* __restrict__ ob) {
    __shared__ ushort_t vs[64 * 64];     // V^T chunk [d][kk]
    __shared__ ushort_t ps[4 * 16 * 64]; // per-wave P tiles
    int bh = blockIdx.x, qt = blockIdx.y;
    int b = bh >> 4, h = bh & 15;
    int tid = threadIdx.x, wave = tid >> 6, lane = tid & 63;
    int l15 = lane & 15, quad = lane >> 4;
    int qrow = qt * 64 + wave * 16;
    ushort_t* pw = ps + wave * 1024;

    const ushort_t* qbase = qb + ((size_t)bh * SEQ + qrow + l15) * DH;
    bf16x8 aq0 = *(const bf16x8*)(qbase + quad * 8);
    bf16x8 aq1 = *(const bf16x8*)(qbase + 32 + quad * 8);

    float qm[4], mrun[4], lrun[4];
    #pragma unroll
    for (int r = 0; r < 4; ++r) {
        qm[r] = (float)mask[b * SEQ + qrow + quad * 4 + r];
        mrun[r] = -3.0e38f; lrun[r] = 0.0f;
    }
    floatx4 oacc[4];
    #pragma unroll
    for (int t = 0; t < 4; ++t) oacc[t] = (floatx4)0.0f;

    for (int kc = 0; kc < SEQ; kc += 64) {
        __syncthreads();   // previous PV reads of vs done
        for (int c = tid; c < 512; c += 256) {
            int d = c >> 3, col = c & 7;
            *(uint4*)(vs + d * 64 + col * 8) =
                *(const uint4*)(vtb + ((size_t)bh * DH + d) * SEQ + kc + col * 8);
        }
        floatx4 s[4];
        #pragma unroll
        for (int j = 0; j < 4; ++j) {
            s[j] = (floatx4)0.0f;
            const ushort_t* kbase = kb + ((size_t)bh * SEQ + kc + j * 16 + l15) * DH;
            s[j] = mfma16(aq0, *(const bf16x8*)(kbase + quad * 8), s[j]);
            s[j] = mfma16(aq1, *(const bf16x8*)(kbase + 32 + quad * 8), s[j]);
        }
        #pragma unroll
        for (int j = 0; j < 4; ++j) {
            float km = (float)mask[b * SEQ + kc + j * 16 + l15];
            #pragma unroll
            for (int r = 0; r < 4; ++r)
                s[j][r] = s[j][r] * INV_SCALE + (1.0f - qm[r] * km) * NEGBIG;
        }
        #pragma unroll
        for (int r = 0; r < 4; ++r) {
            float cm = fmaxf(fmaxf(s[0][r], s[1][r]), fmaxf(s[2][r], s[3][r]));
            #pragma unroll
            for (int off = 1; off < 16; off <<= 1) cm = fmaxf(cm, __shfl_xor(cm, off, 16));
            float nm = fmaxf(mrun[r], cm);
            float alpha = __expf(mrun[r] - nm);
            float psum = 0.0f;
            #pragma unroll
            for (int j = 0; j < 4; ++j) {
                float p = __expf(s[j][r] - nm);
                pw[(quad * 4 + r) * 64 + j * 16 + l15] = f2bf(p);
                psum += p;
            }
            #pragma unroll
            for (int off = 1; off < 16; off <<= 1) psum += __shfl_xor(psum, off, 16);
            lrun[r] = lrun[r] * alpha + psum;
            mrun[r] = nm;
            #pragma unroll
            for (int t = 0; t < 4; ++t) oacc[t][r] *= alpha;
        }
        __syncthreads();   // vs staged & P visible

        bf16x8 pa0 = *(const bf16x8*)(pw + l15 * 64 + quad * 8);
        bf16x8 pa1 = *(const bf16x8*)(pw + l15 * 64 + 32 + quad * 8);
        #pragma unroll
        for (int t = 0; t < 4; ++t) {
            bf16x8 bv0 = *(const bf16x8*)(vs + (t * 16 + l15) * 64 + quad * 8);
            bf16x8 bv1 = *(const bf16x8*)(vs + (t * 16 + l15) * 64 + 32 + quad * 8);
            oacc[t] = mfma16(pa0, bv0, oacc[t]);
            oacc[t] = mfma16(pa1, bv1, oacc[t]);
        }
    }
    float invl[4];
    #pragma unroll
    for (int r = 0; r < 4; ++r) invl[r] = 1.0f / lrun[r];
    #pragma unroll
    for (int t = 0; t < 4; ++t)
        #pragma unroll
        for (int r = 0; r < 4; ++r)
            ob[((size_t)b * SEQ + qrow + quad * 4 + r) * DM + h * DH + t * 16 + l15] =
                f2bf(oacc[t][r] * invl[r]);
    if (l15 == 0) {
        #pragma unroll
        for (int r = 0; r < 4; ++r) {
            int row = qrow + quad * 4 + r;
            mbuf[(size_t)bh * SEQ + row] = mrun[r];
            lbuf[(size_t)bh * SEQ + row] = invl[r];
        }
    }
}

// ---------------- K3b: attn mean over heads (f32 out), k-split grid ----------------
__global__ __launch_bounds__(256, 4) void k_attn_avg(const ushort_t* __restrict__ qb,
                                                     const ushort_t* __restrict__ kb,
                                                     const int* __restrict__ mask,
                                                     const float* __restrict__ mbuf,
                                                     const float* __restrict__ lbuf,
                                                     float* __restrict__ attn_out) {
    int bx = blockIdx.x;                 // 4 b * 64 qt * 4 kq = 1024
    int b  = bx >> 8;
    int qt = (bx >> 2) & 63;
    int kq = bx & 3;
    int q0 = qt * 16;
    int tid = threadIdx.x, wave = tid >> 6, lane = tid & 63;
    int l15 = lane & 15, quad = lane >> 4;
    int kbase = kq * 256 + wave * 64;

    float qmr[4];
    #pragma unroll
    for (int r = 0; r < 4; ++r) qmr[r] = (float)mask[b * SEQ + q0 + quad * 4 + r];

    floatx4 aacc[4];
    #pragma unroll
    for (int j = 0; j < 4; ++j) aacc[j] = (floatx4)0.0f;

    for (int h = 0; h < NH; ++h) {
        int bh = b * NH + h;
        const ushort_t* qbase = qb + ((size_t)bh * SEQ + q0 + l15) * DH;
        bf16x8 aq0 = *(const bf16x8*)(qbase + quad * 8);
        bf16x8 aq1 = *(const bf16x8*)(qbase + 32 + quad * 8);
        float mr[4], il[4];
        #pragma unroll
        for (int r = 0; r < 4; ++r) {
            mr[r] = mbuf[(size_t)bh * SEQ + q0 + quad * 4 + r];
            il[r] = lbuf[(size_t)bh * SEQ + q0 + quad * 4 + r];
        }
        floatx4 s[4];
        #pragma unroll
        for (int j = 0; j < 4; ++j) {
            s[j] = (floatx4)0.0f;
            const ushort_t* kp = kb + ((size_t)bh * SEQ + kbase + j * 16 + l15) * DH;
            s[j] = mfma16(aq0, *(const bf16x8*)(kp + quad * 8), s[j]);
            s[j] = mfma16(aq1, *(const bf16x8*)(kp + 32 + quad * 8), s[j]);
        }
        #pragma unroll
        for (int j = 0; j < 4; ++j) {
            float km = (float)mask[b * SEQ + kbase + j * 16 + l15];
            #pragma unroll
            for (int r = 0; r < 4; ++r) {
                float sv = s[j][r] * INV_SCALE + (1.0f - qmr[r] * km) * NEGBIG;
                aacc[j][r] += __expf(sv - mr[r]) * il[r] * 0.0625f;
            }
        }
    }
    #pragma unroll
    for (int j = 0; j < 4; ++j)
        #pragma unroll
        for (int r = 0; r < 4; ++r)
            attn_out[((size_t)b * SEQ + q0 + quad * 4 + r) * SEQ +
                     kbase + j * 16 + l15] = aacc[j][r];
}

// ---------------- K4: output projection + bias + residual (f32 out) ----------------
__global__ __launch_bounds__(256, 2) void k_proj(const ushort_t* __restrict__ ob,
                                                 const ushort_t* __restrict__ Wpt,
                                                 const float* __restrict__ bias,
                                                 const float* __restrict__ tokens,
                                                 float* __restrict__ out) {
    __shared__ ushort_t smem[8192];
    int m0 = blockIdx.y * 128, n0 = blockIdx.x * 128;
    floatx4 acc[4][4];
    #pragma unroll
    for (int i = 0; i < 4; ++i)
        #pragma unroll
        for (int j = 0; j < 4; ++j) acc[i][j] = (floatx4)0.0f;

    gemm128_body(ob, Wpt, m0, n0, DM, acc, smem);

    int tid = threadIdx.x, wave = tid >> 6, lane = tid & 63;
    int l15 = lane & 15, quad = lane >> 4;
    int wr = (wave >> 1) * 64, wc = (wave & 1) * 64;
    #pragma unroll
    for (int i = 0; i < 4; ++i) {
        int m0r = m0 + wr + i * 16 + quad * 4;
        #pragma unroll
        for (int j = 0; j < 4; ++j) {
            int n = n0 + wc + j * 16 + l15;
            float bv = bias[n];
            #pragma unroll
            for (int r = 0; r < 4; ++r) {
                size_t idx = (size_t)(m0r + r) * DM + n;
                out[idx] = acc[i][j][r] + bv + tokens[idx];
            }
        }
    }
}

extern "C" void kernel_launch(void* const* d_in, const int* in_sizes, int n_in,
                              void* d_out, int out_size, void* d_ws, size_t ws_size,
                              hipStream_t stream) {
    const float* tokens = (const float*)d_in[0];
    const int*   mask   = (const int*)d_in[1];
    const float* Wqkv   = (const float*)d_in[2];
    const float* bqkv   = (const float*)d_in[3];
    const float* Wproj  = (const float*)d_in[4];
    const float* bproj  = (const float*)d_in[5];

    float* out_tok  = (float*)d_out;                   // 4M floats
    float* out_attn = out_tok + (size_t)4 * SEQ * SEQ; // 4M floats

    // scratch inside d_out's attn region (overwritten last by k_attn_avg):
    ushort_t* Xbf  = (ushort_t*)out_attn;                           // 4M bf16
    ushort_t* obuf = (ushort_t*)(out_attn + (size_t)2 * SEQ * SEQ); // 4M bf16

    // ws layout (32.75 MB)
    ushort_t* Wt   = (ushort_t*)d_ws;            // 3072x1024 bf16
    ushort_t* Wpt  = Wt  + (size_t)3 * DM * DM;  // 1024x1024 bf16
    ushort_t* qbuf = Wpt + (size_t)DM * DM;      // (b,h,s,d)
    ushort_t* kbuf = qbuf + (size_t)4 * SEQ * DM;
    ushort_t* vtb  = kbuf + (size_t)4 * SEQ * DM; // (b,h,d,s)
    float*    mbuf = (float*)(vtb + (size_t)4 * SEQ * DM);
    float*    lbuf = mbuf + (size_t)4 * NH * SEQ;

    k_cast<<<(4 * SEQ * DM) / (8 * 256), 256, 0, stream>>>(tokens, Xbf);
    k_transpose<<<dim3(3 * DM / 32, DM / 32), dim3(32, 8), 0, stream>>>(Wqkv, Wt, DM, 3 * DM);
    k_transpose<<<dim3(DM / 32, DM / 32), dim3(32, 8), 0, stream>>>(Wproj, Wpt, DM, DM);
    k_qkv_gemm<<<dim3(24, 32), 256, 0, stream>>>(Xbf, Wt, bqkv, qbuf, kbuf, vtb);
    k_attn_flash<<<dim3(64, 16), 256, 0, stream>>>(qbuf, kbuf, vtb, mask, mbuf, lbuf, obuf);
    k_proj<<<dim3(8, 32), 256, 0, stream>>>(obuf, Wpt, bproj, tokens, out_tok);
    k_attn_avg<<<1024, 256, 0, stream>>>(qbuf, kbuf, mask, mbuf, lbuf, out_attn);
}

// Round 5
// 302.524 us; speedup vs baseline: 1.3234x; 1.0206x over previous
//
#include <hip/hip_runtime.h>
#include <hip/hip_bf16.h>
#include <math.h>

// Problem: B=4, SEQ=1024, D_MODEL=1024, H=16, DH=64.
// Harness dtypes: float32 inputs/outputs, int32 mask. Internal: bf16 MFMA.
#define SEQ   1024
#define DM    1024
#define NH    16
#define DH    64
#define INV_SCALE 0.125f       // 1/sqrt(64)
#define NEGBIG   -1e9f

typedef __attribute__((ext_vector_type(8))) __bf16 bf16x8;
typedef __attribute__((ext_vector_type(4))) float floatx4;
typedef unsigned short ushort_t;

__device__ __forceinline__ floatx4 mfma16(bf16x8 a, bf16x8 b, floatx4 c) {
    return __builtin_amdgcn_mfma_f32_16x16x32_bf16(a, b, c, 0, 0, 0);
}

__device__ __forceinline__ ushort_t f2bf(float f) {
    unsigned int u = __float_as_uint(f);
    u += 0x7fffu + ((u >> 16) & 1u);      // RNE
    return (ushort_t)(u >> 16);
}

__device__ __forceinline__ void gload_lds16(const void* g, void* l) {
    __builtin_amdgcn_global_load_lds(
        (const __attribute__((address_space(1))) unsigned int*)g,
        (__attribute__((address_space(3))) unsigned int*)l, 16, 0, 0);
}

// ---------------- K0: f32 -> bf16 cast (8 elems/thread) ----------------
__global__ __launch_bounds__(256) void k_cast(const float* __restrict__ src,
                                              ushort_t* __restrict__ dst) {
    int i = (blockIdx.x * 256 + threadIdx.x) * 8;
    float4 a = *(const float4*)(src + i);
    float4 b = *(const float4*)(src + i + 4);
    union { ushort_t s[8]; uint4 v; } pk;
    pk.s[0] = f2bf(a.x); pk.s[1] = f2bf(a.y); pk.s[2] = f2bf(a.z); pk.s[3] = f2bf(a.w);
    pk.s[4] = f2bf(b.x); pk.s[5] = f2bf(b.y); pk.s[6] = f2bf(b.z); pk.s[7] = f2bf(b.w);
    *(uint4*)(dst + i) = pk.v;
}

// ---------------- K1: f32 (R x C) -> bf16 transpose (C x R) ----------------
__global__ __launch_bounds__(256) void k_transpose(const float* __restrict__ src,
                                                   ushort_t* __restrict__ dst,
                                                   int R, int C) {
    __shared__ ushort_t tile[32][33];
    int bx = blockIdx.x * 32;
    int by = blockIdx.y * 32;
    for (int i = threadIdx.y; i < 32; i += 8)
        tile[i][threadIdx.x] = f2bf(src[(size_t)(by + i) * C + bx + threadIdx.x]);
    __syncthreads();
    for (int i = threadIdx.y; i < 32; i += 8)
        dst[(size_t)(bx + i) * R + by + threadIdx.x] = tile[threadIdx.x][i];
}

// ------------- shared 128x128 MFMA GEMM body: C = A(MxK) * Bt(NxK)^T -------------
// smem rows: 32 ushorts = 4 chunks of 16B. Physical chunk c of row r holds
// logical chunk c ^ ((r>>1)&3)  -> LDS fragment reads go 8-way -> 2-way (free).
// Swizzle is applied on the global SOURCE column (global_load_lds dest is
// forced to base + lane*16).
__device__ __forceinline__ void gemm128_body(const ushort_t* __restrict__ A,
                                             const ushort_t* __restrict__ Bt,
                                             int m0, int n0, int Kd,
                                             floatx4 acc[4][4], ushort_t* smem) {
    int tid  = threadIdx.x;
    int wave = tid >> 6, lane = tid & 63;
    int l15 = lane & 15, quad = lane >> 4;
    int wr = (wave >> 1) * 64, wc = (wave & 1) * 64;
    int rsub = lane >> 2;                              // row within 16-row chunk
    int ksub = (((lane & 3) ^ ((lane >> 3) & 3)) * 8); // swizzled source chunk
    int rsw  = (l15 >> 1) & 3;                         // read-side swizzle key

    for (int k0 = 0; k0 < Kd; k0 += 32) {
        __syncthreads();   // previous compute done before overwrite
        #pragma unroll
        for (int c = 0; c < 2; ++c) {
            int rbase = wave * 32 + c * 16;
            gload_lds16(A  + (size_t)(m0 + rbase + rsub) * Kd + k0 + ksub,
                        smem + rbase * 32);
            gload_lds16(Bt + (size_t)(n0 + rbase + rsub) * Kd + k0 + ksub,
                        smem + 4096 + rbase * 32);
        }
        __syncthreads();   // compiler drains vmcnt before barrier

        bf16x8 af[4], bfr[4];
        #pragma unroll
        for (int i = 0; i < 4; ++i)
            af[i] = *(const bf16x8*)(smem + (wr + i * 16 + l15) * 32 + (quad ^ rsw) * 8);
        #pragma unroll
        for (int j = 0; j < 4; ++j)
            bfr[j] = *(const bf16x8*)(smem + 4096 + (wc + j * 16 + l15) * 32 + (quad ^ rsw) * 8);
        #pragma unroll
        for (int i = 0; i < 4; ++i)
            #pragma unroll
            for (int j = 0; j < 4; ++j)
                acc[i][j] = mfma16(af[i], bfr[j], acc[i][j]);
    }
}

// ---------------- K2: QKV GEMM, epilogue routes Q/K/(V transposed) ----------------
__global__ __launch_bounds__(256, 2) void k_qkv_gemm(const ushort_t* __restrict__ X,
                                                     const ushort_t* __restrict__ Wt,
                                                     const float* __restrict__ bias,
                                                     ushort_t* __restrict__ qb,
                                                     ushort_t* __restrict__ kb,
                                                     ushort_t* __restrict__ vtb) {
    __shared__ ushort_t smem[8192];
    int m0 = blockIdx.y * 128, n0 = blockIdx.x * 128;
    floatx4 acc[4][4];
    #pragma unroll
    for (int i = 0; i < 4; ++i)
        #pragma unroll
        for (int j = 0; j < 4; ++j) acc[i][j] = (floatx4)0.0f;

    gemm128_body(X, Wt, m0, n0, DM, acc, smem);

    int tid = threadIdx.x, wave = tid >> 6, lane = tid & 63;
    int l15 = lane & 15, quad = lane >> 4;
    int wr = (wave >> 1) * 64, wc = (wave & 1) * 64;
    #pragma unroll
    for (int i = 0; i < 4; ++i) {
        int mrow0 = m0 + wr + i * 16 + quad * 4;     // multiple of 4, no b-crossing
        int b = mrow0 >> 10, t0 = mrow0 & 1023;
        #pragma unroll
        for (int j = 0; j < 4; ++j) {
            int n = n0 + wc + j * 16 + l15;
            float bv = bias[n];
            int sec = n >> 10, nn = n & 1023;
            int h = nn >> 6, d = nn & 63;
            if (sec == 2) {
                union { ushort_t s[4]; uint2 v; } pk;
                #pragma unroll
                for (int r = 0; r < 4; ++r) pk.s[r] = f2bf(acc[i][j][r] + bv);
                *(uint2*)(vtb + (((size_t)(b * NH + h) * DH + d) * SEQ + t0)) = pk.v;
            } else {
                ushort_t* dst = (sec == 0) ? qb : kb;
                #pragma unroll
                for (int r = 0; r < 4; ++r)
                    dst[((size_t)(b * NH + h) * SEQ + t0 + r) * DH + d] =
                        f2bf(acc[i][j][r] + bv);
            }
        }
    }
}

// ---------------- K3: flash attention — online softmax, O = P@V, writes m & 1/l ----
// vs/ps rows: 64 ushorts = 8 chunks of 16B; physical chunk = logical ^ (row&7)
// -> b128 fragment reads 16-way -> 2-way (free).
__global__ __launch_bounds__(256, 4) void k_attn_flash(const ushort_t* __restrict__ qb,
                                                       const ushort_t* __restrict__ kb,
                                                       const ushort_t* __restrict__ vtb,
                                                       const int* __restrict__ mask,
                                                       float* __restrict__ mbuf,
                                                       float* __restrict__ lbuf,
                                                       ushort_t* __restrict__ ob) {
    __shared__ ushort_t vs[64 * 64];     // V^T chunk [d][kk], swizzled
    __shared__ ushort_t ps[4 * 16 * 64]; // per-wave P tiles, swizzled
    int bh = blockIdx.x, qt = blockIdx.y;
    int b = bh >> 4, h = bh & 15;
    int tid = threadIdx.x, wave = tid >> 6, lane = tid & 63;
    int l15 = lane & 15, quad = lane >> 4;
    int qrow = qt * 64 + wave * 16;
    ushort_t* pw = ps + wave * 1024;
    int sw7 = l15 & 7;                     // read-side swizzle key (row = l15)

    const ushort_t* qbase = qb + ((size_t)bh * SEQ + qrow + l15) * DH;
    bf16x8 aq0 = *(const bf16x8*)(qbase + quad * 8);
    bf16x8 aq1 = *(const bf16x8*)(qbase + 32 + quad * 8);

    float qm[4], mrun[4], lrun[4];
    #pragma unroll
    for (int r = 0; r < 4; ++r) {
        qm[r] = (float)mask[b * SEQ + qrow + quad * 4 + r];
        mrun[r] = -3.0e38f; lrun[r] = 0.0f;
    }
    floatx4 oacc[4];
    #pragma unroll
    for (int t = 0; t < 4; ++t) oacc[t] = (floatx4)0.0f;

    for (int kc = 0; kc < SEQ; kc += 64) {
        __syncthreads();   // previous PV reads of vs done
        for (int c = tid; c < 512; c += 256) {
            int d = c >> 3, col = c & 7;
            *(uint4*)(vs + d * 64 + ((col ^ (d & 7)) * 8)) =
                *(const uint4*)(vtb + ((size_t)bh * DH + d) * SEQ + kc + col * 8);
        }
        floatx4 s[4];
        #pragma unroll
        for (int j = 0; j < 4; ++j) {
            s[j] = (floatx4)0.0f;
            const ushort_t* kbase = kb + ((size_t)bh * SEQ + kc + j * 16 + l15) * DH;
            s[j] = mfma16(aq0, *(const bf16x8*)(kbase + quad * 8), s[j]);
            s[j] = mfma16(aq1, *(const bf16x8*)(kbase + 32 + quad * 8), s[j]);
        }
        #pragma unroll
        for (int j = 0; j < 4; ++j) {
            float km = (float)mask[b * SEQ + kc + j * 16 + l15];
            #pragma unroll
            for (int r = 0; r < 4; ++r)
                s[j][r] = s[j][r] * INV_SCALE + (1.0f - qm[r] * km) * NEGBIG;
        }
        #pragma unroll
        for (int r = 0; r < 4; ++r) {
            float cm = fmaxf(fmaxf(s[0][r], s[1][r]), fmaxf(s[2][r], s[3][r]));
            #pragma unroll
            for (int off = 1; off < 16; off <<= 1) cm = fmaxf(cm, __shfl_xor(cm, off, 16));
            float nm = fmaxf(mrun[r], cm);
            float alpha = __expf(mrun[r] - nm);
            float psum = 0.0f;
            int rd = quad * 4 + r;         // P-tile row (C-layout)
            #pragma unroll
            for (int j = 0; j < 4; ++j) {
                float p = __expf(s[j][r] - nm);
                int ch = (2 * j + (l15 >> 3)) ^ (rd & 7);
                pw[rd * 64 + ch * 8 + (l15 & 7)] = f2bf(p);
                psum += p;
            }
            #pragma unroll
            for (int off = 1; off < 16; off <<= 1) psum += __shfl_xor(psum, off, 16);
            lrun[r] = lrun[r] * alpha + psum;
            mrun[r] = nm;
            #pragma unroll
            for (int t = 0; t < 4; ++t) oacc[t][r] *= alpha;
        }
        __syncthreads();   // vs staged & P visible

        bf16x8 pa0 = *(const bf16x8*)(pw + l15 * 64 + ((quad ^ sw7) * 8));
        bf16x8 pa1 = *(const bf16x8*)(pw + l15 * 64 + (((quad + 4) ^ sw7) * 8));
        #pragma unroll
        for (int t = 0; t < 4; ++t) {
            bf16x8 bv0 = *(const bf16x8*)(vs + (t * 16 + l15) * 64 + ((quad ^ sw7) * 8));
            bf16x8 bv1 = *(const bf16x8*)(vs + (t * 16 + l15) * 64 + (((quad + 4) ^ sw7) * 8));
            oacc[t] = mfma16(pa0, bv0, oacc[t]);
            oacc[t] = mfma16(pa1, bv1, oacc[t]);
        }
    }
    float invl[4];
    #pragma unroll
    for (int r = 0; r < 4; ++r) invl[r] = 1.0f / lrun[r];
    #pragma unroll
    for (int t = 0; t < 4; ++t)
        #pragma unroll
        for (int r = 0; r < 4; ++r)
            ob[((size_t)b * SEQ + qrow + quad * 4 + r) * DM + h * DH + t * 16 + l15] =
                f2bf(oacc[t][r] * invl[r]);
    if (l15 == 0) {
        #pragma unroll
        for (int r = 0; r < 4; ++r) {
            int row = qrow + quad * 4 + r;
            mbuf[(size_t)bh * SEQ + row] = mrun[r];
            lbuf[(size_t)bh * SEQ + row] = invl[r];
        }
    }
}

// ---------------- K3b: attn mean over heads (f32 out), k-split grid ----------------
__global__ __launch_bounds__(256, 4) void k_attn_avg(const ushort_t* __restrict__ qb,
                                                     const ushort_t* __restrict__ kb,
                                                     const int* __restrict__ mask,
                                                     const float* __restrict__ mbuf,
                                                     const float* __restrict__ lbuf,
                                                     float* __restrict__ attn_out) {
    int bx = blockIdx.x;                 // 4 b * 64 qt * 4 kq = 1024
    int b  = bx >> 8;
    int qt = (bx >> 2) & 63;
    int kq = bx & 3;
    int q0 = qt * 16;
    int tid = threadIdx.x, wave = tid >> 6, lane = tid & 63;
    int l15 = lane & 15, quad = lane >> 4;
    int kbase = kq * 256 + wave * 64;

    float qmr[4];
    #pragma unroll
    for (int r = 0; r < 4; ++r) qmr[r] = (float)mask[b * SEQ + q0 + quad * 4 + r];

    floatx4 aacc[4];
    #pragma unroll
    for (int j = 0; j < 4; ++j) aacc[j] = (floatx4)0.0f;

    for (int h = 0; h < NH; ++h) {
        int bh = b * NH + h;
        const ushort_t* qbase = qb + ((size_t)bh * SEQ + q0 + l15) * DH;
        bf16x8 aq0 = *(const bf16x8*)(qbase + quad * 8);
        bf16x8 aq1 = *(const bf16x8*)(qbase + 32 + quad * 8);
        float mr[4], il[4];
        #pragma unroll
        for (int r = 0; r < 4; ++r) {
            mr[r] = mbuf[(size_t)bh * SEQ + q0 + quad * 4 + r];
            il[r] = lbuf[(size_t)bh * SEQ + q0 + quad * 4 + r];
        }
        floatx4 s[4];
        #pragma unroll
        for (int j = 0; j < 4; ++j) {
            s[j] = (floatx4)0.0f;
            const ushort_t* kp = kb + ((size_t)bh * SEQ + kbase + j * 16 + l15) * DH;
            s[j] = mfma16(aq0, *(const bf16x8*)(kp + quad * 8), s[j]);
            s[j] = mfma16(aq1, *(const bf16x8*)(kp + 32 + quad * 8), s[j]);
        }
        #pragma unroll
        for (int j = 0; j < 4; ++j) {
            float km = (float)mask[b * SEQ + kbase + j * 16 + l15];
            #pragma unroll
            for (int r = 0; r < 4; ++r) {
                float sv = s[j][r] * INV_SCALE + (1.0f - qmr[r] * km) * NEGBIG;
                aacc[j][r] += __expf(sv - mr[r]) * il[r] * 0.0625f;
            }
        }
    }
    #pragma unroll
    for (int j = 0; j < 4; ++j)
        #pragma unroll
        for (int r = 0; r < 4; ++r)
            attn_out[((size_t)b * SEQ + q0 + quad * 4 + r) * SEQ +
                     kbase + j * 16 + l15] = aacc[j][r];
}

// ---------------- K4: output projection + bias + residual (f32 out) ----------------
__global__ __launch_bounds__(256, 2) void k_proj(const ushort_t* __restrict__ ob,
                                                 const ushort_t* __restrict__ Wpt,
                                                 const float* __restrict__ bias,
                                                 const float* __restrict__ tokens,
                                                 float* __restrict__ out) {
    __shared__ ushort_t smem[8192];
    int m0 = blockIdx.y * 128, n0 = blockIdx.x * 128;
    floatx4 acc[4][4];
    #pragma unroll
    for (int i = 0; i < 4; ++i)
        #pragma unroll
        for (int j = 0; j < 4; ++j) acc[i][j] = (floatx4)0.0f;

    gemm128_body(ob, Wpt, m0, n0, DM, acc, smem);

    int tid = threadIdx.x, wave = tid >> 6, lane = tid & 63;
    int l15 = lane & 15, quad = lane >> 4;
    int wr = (wave >> 1) * 64, wc = (wave & 1) * 64;
    #pragma unroll
    for (int i = 0; i < 4; ++i) {
        int m0r = m0 + wr + i * 16 + quad * 4;
        #pragma unroll
        for (int j = 0; j < 4; ++j) {
            int n = n0 + wc + j * 16 + l15;
            float bv = bias[n];
            #pragma unroll
            for (int r = 0; r < 4; ++r) {
                size_t idx = (size_t)(m0r + r) * DM + n;
                out[idx] = acc[i][j][r] + bv + tokens[idx];
            }
        }
    }
}

extern "C" void kernel_launch(void* const* d_in, const int* in_sizes, int n_in,
                              void* d_out, int out_size, void* d_ws, size_t ws_size,
                              hipStream_t stream) {
    const float* tokens = (const float*)d_in[0];
    const int*   mask   = (const int*)d_in[1];
    const float* Wqkv   = (const float*)d_in[2];
    const float* bqkv   = (const float*)d_in[3];
    const float* Wproj  = (const float*)d_in[4];
    const float* bproj  = (const float*)d_in[5];

    float* out_tok  = (float*)d_out;                   // 4M floats
    float* out_attn = out_tok + (size_t)4 * SEQ * SEQ; // 4M floats

    // scratch inside d_out's attn region (overwritten last by k_attn_avg):
    ushort_t* Xbf  = (ushort_t*)out_attn;                           // 4M bf16
    ushort_t* obuf = (ushort_t*)(out_attn + (size_t)2 * SEQ * SEQ); // 4M bf16

    // ws layout (32.75 MB)
    ushort_t* Wt   = (ushort_t*)d_ws;            // 3072x1024 bf16
    ushort_t* Wpt  = Wt  + (size_t)3 * DM * DM;  // 1024x1024 bf16
    ushort_t* qbuf = Wpt + (size_t)DM * DM;      // (b,h,s,d)
    ushort_t* kbuf = qbuf + (size_t)4 * SEQ * DM;
    ushort_t* vtb  = kbuf + (size_t)4 * SEQ * DM; // (b,h,d,s)
    float*    mbuf = (float*)(vtb + (size_t)4 * SEQ * DM);
    float*    lbuf = mbuf + (size_t)4 * NH * SEQ;

    k_cast<<<(4 * SEQ * DM) / (8 * 256), 256, 0, stream>>>(tokens, Xbf);
    k_transpose<<<dim3(3 * DM / 32, DM / 32), dim3(32, 8), 0, stream>>>(Wqkv, Wt, DM, 3 * DM);
    k_transpose<<<dim3(DM / 32, DM / 32), dim3(32, 8), 0, stream>>>(Wproj, Wpt, DM, DM);
    k_qkv_gemm<<<dim3(24, 32), 256, 0, stream>>>(Xbf, Wt, bqkv, qbuf, kbuf, vtb);
    k_attn_flash<<<dim3(64, 16), 256, 0, stream>>>(qbuf, kbuf, vtb, mask, mbuf, lbuf, obuf);
    k_proj<<<dim3(8, 32), 256, 0, stream>>>(obuf, Wpt, bproj, tokens, out_tok);
    k_attn_avg<<<1024, 256, 0, stream>>>(qbuf, kbuf, mask, mbuf, lbuf, out_attn);
}